// Round 1
// baseline (274.472 us; speedup 1.0000x reference)
//
#include <hip/hip_runtime.h>
#include <stdint.h>

#define TDIM 4096   // tokens = 2*2048
#define KDIM 4096   // IN_F
#define NDIM 4096   // OUT_F
#define RANK 128
#define NG   32

typedef __attribute__((ext_vector_type(4))) int i32x4;

__device__ inline void fma4(float4& a, float s, const float4& b) {
    a.x = fmaf(s, b.x, a.x);
    a.y = fmaf(s, b.y, a.y);
    a.z = fmaf(s, b.z, a.z);
    a.w = fmaf(s, b.w, a.w);
}

// ---------------------------------------------------------------------------
// Kernel 1: per-token activation quantization.
// One block per token row; row buffered in LDS so x is read once.
// x_q = clip(rint(x / (rowmax/127)), -128, 127)
// ---------------------------------------------------------------------------
__global__ __launch_bounds__(256) void quant_x_kernel(
    const float* __restrict__ x, int8_t* __restrict__ xq,
    float* __restrict__ scale_x)
{
    const int row = blockIdx.x;
    const float* xr = x + (size_t)row * KDIM;
    __shared__ float buf[KDIM];     // 16 KB
    __shared__ float wred[4];

    float m = 0.f;
    for (int j = threadIdx.x; j < KDIM; j += 256) {
        float v = xr[j];
        buf[j] = v;
        m = fmaxf(m, fabsf(v));
    }
    #pragma unroll
    for (int off = 32; off > 0; off >>= 1)
        m = fmaxf(m, __shfl_xor(m, off, 64));
    if ((threadIdx.x & 63) == 0) wred[threadIdx.x >> 6] = m;
    __syncthreads();
    const float mt = fmaxf(fmaxf(wred[0], wred[1]), fmaxf(wred[2], wred[3]));
    const float sx = mt / 127.0f;
    if (threadIdx.x == 0) scale_x[row] = sx;

    for (int j = threadIdx.x; j < KDIM; j += 256) {
        float q = rintf(buf[j] / sx);          // true division: match jnp rounding
        q = fminf(fmaxf(q, -128.f), 127.f);
        xq[(size_t)row * KDIM + j] = (int8_t)q;
    }
}

// ---------------------------------------------------------------------------
// Kernel 2: dequantize W (HQQ group dequant + rank-128 SVD correction),
// write Wf fp32 to scratch (d_out reused), and per-out-row max -> scale_w.
// Block handles 16 out-rows x all 4096 in-cols. svd_up tile in LDS;
// i processed 4-wide (float4) so each LDS up-read amortizes over 4 cols.
// ---------------------------------------------------------------------------
__global__ __launch_bounds__(256) void w_pass1_kernel(
    const int* __restrict__ Wq, const float* __restrict__ scale,
    const float* __restrict__ zp, const float* __restrict__ svd_up,
    const float* __restrict__ svd_down,
    float* __restrict__ Wf, float* __restrict__ scale_w)
{
    const int o0 = blockIdx.x * 16;
    __shared__ __align__(16) float up_s[16][RANK];   // 8 KB
    __shared__ float red[16][4];

    for (int idx = threadIdx.x; idx < 16 * RANK; idx += 256)
        up_s[idx >> 7][idx & 127] = svd_up[(size_t)o0 * RANK + idx];
    __syncthreads();

    float rmax[16];
    #pragma unroll
    for (int m = 0; m < 16; ++m) rmax[m] = 0.f;

    for (int c = 0; c < 4; ++c) {
        const int i = c * 1024 + threadIdx.x * 4;

        float4 sv[16];
        #pragma unroll
        for (int m = 0; m < 16; ++m) sv[m] = make_float4(0.f, 0.f, 0.f, 0.f);

        for (int r4 = 0; r4 < RANK; r4 += 4) {
            const float4 d0 = *(const float4*)(svd_down + (size_t)(r4 + 0) * KDIM + i);
            const float4 d1 = *(const float4*)(svd_down + (size_t)(r4 + 1) * KDIM + i);
            const float4 d2 = *(const float4*)(svd_down + (size_t)(r4 + 2) * KDIM + i);
            const float4 d3 = *(const float4*)(svd_down + (size_t)(r4 + 3) * KDIM + i);
            #pragma unroll
            for (int m = 0; m < 16; ++m) {
                const float4 u = *(const float4*)(&up_s[m][r4]);
                fma4(sv[m], u.x, d0);
                fma4(sv[m], u.y, d1);
                fma4(sv[m], u.z, d2);
                fma4(sv[m], u.w, d3);
            }
        }

        const int g = i >> 7;   // group index (i..i+3 always within one group)
        #pragma unroll
        for (int m = 0; m < 16; ++m) {
            const int o = o0 + m;
            const int4 q4 = *(const int4*)(Wq + (size_t)o * KDIM + i);
            const float s = scale[o * NG + g];
            const float z = zp[o * NG + g];
            float4 wf;
            wf.x = ((float)q4.x - z) * s + sv[m].x;
            wf.y = ((float)q4.y - z) * s + sv[m].y;
            wf.z = ((float)q4.z - z) * s + sv[m].z;
            wf.w = ((float)q4.w - z) * s + sv[m].w;
            *(float4*)(Wf + (size_t)o * KDIM + i) = wf;
            rmax[m] = fmaxf(rmax[m],
                        fmaxf(fmaxf(fabsf(wf.x), fabsf(wf.y)),
                              fmaxf(fabsf(wf.z), fabsf(wf.w))));
        }
    }

    const int lane = threadIdx.x & 63, wv = threadIdx.x >> 6;
    #pragma unroll
    for (int m = 0; m < 16; ++m) {
        float v = rmax[m];
        #pragma unroll
        for (int off = 32; off > 0; off >>= 1)
            v = fmaxf(v, __shfl_xor(v, off, 64));
        if (lane == 0) red[m][wv] = v;
    }
    __syncthreads();
    if (threadIdx.x < 16) {
        const float v = fmaxf(fmaxf(red[threadIdx.x][0], red[threadIdx.x][1]),
                              fmaxf(red[threadIdx.x][2], red[threadIdx.x][3]));
        scale_w[o0 + threadIdx.x] = v / 127.0f;
    }
}

// ---------------------------------------------------------------------------
// Kernel 3: quantize Wf -> w_q int8, stored [out][in] (B-transposed for GEMM).
// ---------------------------------------------------------------------------
__global__ __launch_bounds__(256) void w_quant_kernel(
    const float* __restrict__ Wf, const float* __restrict__ scale_w,
    int8_t* __restrict__ wq)
{
    const size_t idx = ((size_t)blockIdx.x * 256 + threadIdx.x) * 4;
    const int o = (int)(idx >> 12);
    const float sw = scale_w[o];
    const float4 wf = *(const float4*)(Wf + idx);
    char4 q;
    q.x = (char)fminf(fmaxf(rintf(wf.x / sw), -128.f), 127.f);
    q.y = (char)fminf(fmaxf(rintf(wf.y / sw), -128.f), 127.f);
    q.z = (char)fminf(fmaxf(rintf(wf.z / sw), -128.f), 127.f);
    q.w = (char)fminf(fmaxf(rintf(wf.w / sw), -128.f), 127.f);
    *(char4*)(wq + idx) = q;
}

// ---------------------------------------------------------------------------
// Kernel 4: int8 GEMM + epilogue.
// C[t,o] = (sum_k xq[t,k]*wq[o,k]) * sx[t] * sw[o] + bias[o]
// 128x128 tile, BK=64, 4 waves (2x2), mfma_i32_16x16x64_i8.
// LDS rows padded to 80 B (<=2-way bank conflicts on b128 reads/writes).
// ---------------------------------------------------------------------------
__global__ __launch_bounds__(256) void gemm_i8_kernel(
    const int8_t* __restrict__ Aq,   // [T][K]
    const int8_t* __restrict__ Bq,   // [N][K]
    const float* __restrict__ scale_x, const float* __restrict__ scale_w,
    const float* __restrict__ bias, float* __restrict__ out)
{
    __shared__ __align__(16) int8_t As[128 * 80];
    __shared__ __align__(16) int8_t Bs[128 * 80];

    const int tid = threadIdx.x;
    const int bn = blockIdx.x & 31, bm = blockIdx.x >> 5;
    const int row0 = bm * 128, col0 = bn * 128;

    // staging: each thread moves 2x16B for A and for B per K-step
    const int srow = tid >> 2;            // 0..63
    const int scol = (tid & 3) * 16;      // 0,16,32,48
    const size_t a_base = (size_t)(row0 + srow) * KDIM + scol;
    const size_t b_base = (size_t)(col0 + srow) * KDIM + scol;

    const int lane = tid & 63;
    const int wid  = tid >> 6;
    const int wm = (wid >> 1) * 64, wn = (wid & 1) * 64;
    const int l15 = lane & 15, l16 = lane >> 4;

    const i32x4 zero = {0, 0, 0, 0};
    i32x4 acc[4][4];
    #pragma unroll
    for (int m = 0; m < 4; ++m)
        #pragma unroll
        for (int n = 0; n < 4; ++n) acc[m][n] = zero;

    for (int kt = 0; kt < KDIM; kt += 64) {
        const i32x4 a0 = *(const i32x4*)(Aq + a_base + kt);
        const i32x4 a1 = *(const i32x4*)(Aq + a_base + (size_t)64 * KDIM + kt);
        const i32x4 b0 = *(const i32x4*)(Bq + b_base + kt);
        const i32x4 b1 = *(const i32x4*)(Bq + b_base + (size_t)64 * KDIM + kt);
        __syncthreads();   // previous iteration's LDS reads complete
        *(i32x4*)(&As[srow * 80 + scol]) = a0;
        *(i32x4*)(&As[(srow + 64) * 80 + scol]) = a1;
        *(i32x4*)(&Bs[srow * 80 + scol]) = b0;
        *(i32x4*)(&Bs[(srow + 64) * 80 + scol]) = b1;
        __syncthreads();   // staging complete

        i32x4 af[4], bf[4];
        #pragma unroll
        for (int m = 0; m < 4; ++m)
            af[m] = *(const i32x4*)(&As[(wm + m * 16 + l15) * 80 + l16 * 16]);
        #pragma unroll
        for (int n = 0; n < 4; ++n)
            bf[n] = *(const i32x4*)(&Bs[(wn + n * 16 + l15) * 80 + l16 * 16]);

        #pragma unroll
        for (int m = 0; m < 4; ++m)
            #pragma unroll
            for (int n = 0; n < 4; ++n)
                acc[m][n] = __builtin_amdgcn_mfma_i32_16x16x64_i8(
                                af[m], bf[n], acc[m][n], 0, 0, 0);
    }

    // epilogue: C/D layout col = lane&15, row = (lane>>4)*4 + reg
    #pragma unroll
    for (int m = 0; m < 4; ++m) {
        #pragma unroll
        for (int n = 0; n < 4; ++n) {
            const int col = col0 + wn + n * 16 + l15;
            const float sw = scale_w[col];
            const float bv = bias[col];
            #pragma unroll
            for (int r = 0; r < 4; ++r) {
                const int row = row0 + wm + m * 16 + l16 * 4 + r;
                const float sx = scale_x[row];
                out[(size_t)row * NDIM + col] =
                    (float)acc[m][n][r] * sx * sw + bv;
            }
        }
    }
}

// ---------------------------------------------------------------------------
extern "C" void kernel_launch(void* const* d_in, const int* in_sizes, int n_in,
                              void* d_out, int out_size, void* d_ws, size_t ws_size,
                              hipStream_t stream)
{
    const float* x        = (const float*)d_in[0];
    const int*   Wq       = (const int*)d_in[1];
    const float* scale    = (const float*)d_in[2];
    const float* zp       = (const float*)d_in[3];
    const float* svd_up   = (const float*)d_in[4];
    const float* svd_down = (const float*)d_in[5];
    const float* bias     = (const float*)d_in[6];
    float* out = (float*)d_out;

    // workspace layout: xq 16MB | wq 16MB | scale_x 16KB | scale_w 16KB
    int8_t* xq = (int8_t*)d_ws;
    int8_t* wq = (int8_t*)d_ws + ((size_t)16 << 20);
    float* scale_x = (float*)((char*)d_ws + ((size_t)32 << 20));
    float* scale_w = scale_x + TDIM;

    // d_out doubles as fp32 Wf scratch (64MB) — fully overwritten by the GEMM.
    float* Wf = out;

    quant_x_kernel<<<TDIM, 256, 0, stream>>>(x, xq, scale_x);
    w_pass1_kernel<<<NDIM / 16, 256, 0, stream>>>(Wq, scale, zp, svd_up,
                                                  svd_down, Wf, scale_w);
    w_quant_kernel<<<(size_t)NDIM * KDIM / (256 * 4), 256, 0, stream>>>(Wf, scale_w, wq);
    gemm_i8_kernel<<<(TDIM / 128) * (NDIM / 128), 256, 0, stream>>>(
        xq, wq, scale_x, scale_w, bias, out);
}

// Round 2
// 217.633 us; speedup vs baseline: 1.2612x; 1.2612x over previous
//
#include <hip/hip_runtime.h>
#include <stdint.h>

#define TDIM 4096   // tokens = 2*2048
#define KDIM 4096   // IN_F
#define NDIM 4096   // OUT_F
#define RANK 128
#define NG   32
#define NCHUNK 4    // col-chunks in w_pass1 (1024 cols each)

typedef __attribute__((ext_vector_type(4))) int i32x4;

__device__ inline void fma4(float4& a, float s, const float4& b) {
    a.x = fmaf(s, b.x, a.x);
    a.y = fmaf(s, b.y, a.y);
    a.z = fmaf(s, b.z, a.z);
    a.w = fmaf(s, b.w, a.w);
}

// ---------------------------------------------------------------------------
// Kernel 1: per-token activation quantization.
// One block per token row; row buffered in LDS so x is read once.
// ---------------------------------------------------------------------------
__global__ __launch_bounds__(256) void quant_x_kernel(
    const float* __restrict__ x, int8_t* __restrict__ xq,
    float* __restrict__ scale_x)
{
    const int row = blockIdx.x;
    const float* xr = x + (size_t)row * KDIM;
    __shared__ float buf[KDIM];     // 16 KB
    __shared__ float wred[4];

    float m = 0.f;
    for (int j = threadIdx.x; j < KDIM; j += 256) {
        float v = xr[j];
        buf[j] = v;
        m = fmaxf(m, fabsf(v));
    }
    #pragma unroll
    for (int off = 32; off > 0; off >>= 1)
        m = fmaxf(m, __shfl_xor(m, off, 64));
    if ((threadIdx.x & 63) == 0) wred[threadIdx.x >> 6] = m;
    __syncthreads();
    const float mt = fmaxf(fmaxf(wred[0], wred[1]), fmaxf(wred[2], wred[3]));
    const float sx = mt / 127.0f;
    if (threadIdx.x == 0) scale_x[row] = sx;

    for (int j = threadIdx.x; j < KDIM; j += 256) {
        float q = rintf(buf[j] / sx);          // true division: match jnp rounding
        q = fminf(fmaxf(q, -128.f), 127.f);
        xq[(size_t)row * KDIM + j] = (int8_t)q;
    }
}

// ---------------------------------------------------------------------------
// Kernel 2: dequantize W (HQQ group dequant + rank-128 SVD correction),
// write Wf fp32 (d_out reused as scratch) + per-(row,chunk) partial max.
// Grid (256,4): blockIdx.x = 16-row group, blockIdx.y = 1024-col chunk.
// 1024 blocks -> 4 blocks/CU -> 16 waves/CU (R0 had 1 wave/SIMD: latency-bound).
// ---------------------------------------------------------------------------
__global__ __launch_bounds__(256) void w_pass1_kernel(
    const int* __restrict__ Wq, const float* __restrict__ scale,
    const float* __restrict__ zp, const float* __restrict__ svd_up,
    const float* __restrict__ svd_down,
    float* __restrict__ Wf, float* __restrict__ partial_max)
{
    const int o0 = blockIdx.x * 16;
    const int chunk = blockIdx.y;
    const int i = chunk * 1024 + threadIdx.x * 4;   // this thread's float4 col
    __shared__ __align__(16) float up_s[16][RANK];  // 8 KB
    __shared__ float red[16][4];

    for (int idx = threadIdx.x; idx < 16 * RANK; idx += 256)
        up_s[idx >> 7][idx & 127] = svd_up[(size_t)o0 * RANK + idx];
    __syncthreads();

    float4 sv[16];
    #pragma unroll
    for (int m = 0; m < 16; ++m) sv[m] = make_float4(0.f, 0.f, 0.f, 0.f);

    for (int r4 = 0; r4 < RANK; r4 += 4) {
        const float4 d0 = *(const float4*)(svd_down + (size_t)(r4 + 0) * KDIM + i);
        const float4 d1 = *(const float4*)(svd_down + (size_t)(r4 + 1) * KDIM + i);
        const float4 d2 = *(const float4*)(svd_down + (size_t)(r4 + 2) * KDIM + i);
        const float4 d3 = *(const float4*)(svd_down + (size_t)(r4 + 3) * KDIM + i);
        #pragma unroll
        for (int m = 0; m < 16; ++m) {
            const float4 u = *(const float4*)(&up_s[m][r4]);   // broadcast read
            fma4(sv[m], u.x, d0);
            fma4(sv[m], u.y, d1);
            fma4(sv[m], u.z, d2);
            fma4(sv[m], u.w, d3);
        }
    }

    const int g = i >> 7;   // 4-aligned i never straddles a 128-wide group
    float rmax[16];
    #pragma unroll
    for (int m = 0; m < 16; ++m) {
        const int o = o0 + m;
        const int4 q4 = *(const int4*)(Wq + (size_t)o * KDIM + i);
        const float s = scale[o * NG + g];
        const float z = zp[o * NG + g];
        float4 wf;
        wf.x = ((float)q4.x - z) * s + sv[m].x;
        wf.y = ((float)q4.y - z) * s + sv[m].y;
        wf.z = ((float)q4.z - z) * s + sv[m].z;
        wf.w = ((float)q4.w - z) * s + sv[m].w;
        *(float4*)(Wf + (size_t)o * KDIM + i) = wf;
        rmax[m] = fmaxf(fmaxf(fabsf(wf.x), fabsf(wf.y)),
                        fmaxf(fabsf(wf.z), fabsf(wf.w)));
    }

    const int lane = threadIdx.x & 63, wv = threadIdx.x >> 6;
    #pragma unroll
    for (int m = 0; m < 16; ++m) {
        float v = rmax[m];
        #pragma unroll
        for (int off = 32; off > 0; off >>= 1)
            v = fmaxf(v, __shfl_xor(v, off, 64));
        if (lane == 0) red[m][wv] = v;
    }
    __syncthreads();
    if (threadIdx.x < 16) {
        const float v = fmaxf(fmaxf(red[threadIdx.x][0], red[threadIdx.x][1]),
                              fmaxf(red[threadIdx.x][2], red[threadIdx.x][3]));
        partial_max[(size_t)(o0 + threadIdx.x) * NCHUNK + chunk] = v;
    }
}

// ---------------------------------------------------------------------------
// Kernel 2b: reduce per-chunk partial maxes -> scale_w (float, /127).
// ---------------------------------------------------------------------------
__global__ __launch_bounds__(256) void finalize_sw_kernel(
    const float* __restrict__ partial_max, float* __restrict__ scale_w)
{
    const int o = blockIdx.x * 256 + threadIdx.x;
    const float* p = partial_max + (size_t)o * NCHUNK;
    scale_w[o] = fmaxf(fmaxf(p[0], p[1]), fmaxf(p[2], p[3])) / 127.0f;
}

// ---------------------------------------------------------------------------
// Kernel 3: quantize Wf -> w_q int8, stored [out][in] (B-transposed for GEMM).
// ---------------------------------------------------------------------------
__global__ __launch_bounds__(256) void w_quant_kernel(
    const float* __restrict__ Wf, const float* __restrict__ scale_w,
    int8_t* __restrict__ wq)
{
    const size_t idx = ((size_t)blockIdx.x * 256 + threadIdx.x) * 4;
    const int o = (int)(idx >> 12);
    const float sw = scale_w[o];
    const float4 wf = *(const float4*)(Wf + idx);
    char4 q;
    q.x = (char)fminf(fmaxf(rintf(wf.x / sw), -128.f), 127.f);
    q.y = (char)fminf(fmaxf(rintf(wf.y / sw), -128.f), 127.f);
    q.z = (char)fminf(fmaxf(rintf(wf.z / sw), -128.f), 127.f);
    q.w = (char)fminf(fmaxf(rintf(wf.w / sw), -128.f), 127.f);
    *(char4*)(wq + idx) = q;
}

// ---------------------------------------------------------------------------
// Kernel 4: int8 GEMM + epilogue.
// C[t,o] = (sum_k xq[t,k]*wq[o,k]) * sx[t] * sw[o] + bias[o]
// 128x128 tile, BK=64, 4 waves (2x2), mfma_i32_16x16x64_i8.
// ---------------------------------------------------------------------------
__global__ __launch_bounds__(256) void gemm_i8_kernel(
    const int8_t* __restrict__ Aq,   // [T][K]
    const int8_t* __restrict__ Bq,   // [N][K]
    const float* __restrict__ scale_x, const float* __restrict__ scale_w,
    const float* __restrict__ bias, float* __restrict__ out)
{
    __shared__ __align__(16) int8_t As[128 * 80];
    __shared__ __align__(16) int8_t Bs[128 * 80];

    const int tid = threadIdx.x;
    const int bn = blockIdx.x & 31, bm = blockIdx.x >> 5;
    const int row0 = bm * 128, col0 = bn * 128;

    const int srow = tid >> 2;            // 0..63
    const int scol = (tid & 3) * 16;      // 0,16,32,48
    const size_t a_base = (size_t)(row0 + srow) * KDIM + scol;
    const size_t b_base = (size_t)(col0 + srow) * KDIM + scol;

    const int lane = tid & 63;
    const int wid  = tid >> 6;
    const int wm = (wid >> 1) * 64, wn = (wid & 1) * 64;
    const int l15 = lane & 15, l16 = lane >> 4;

    const i32x4 zero = {0, 0, 0, 0};
    i32x4 acc[4][4];
    #pragma unroll
    for (int m = 0; m < 4; ++m)
        #pragma unroll
        for (int n = 0; n < 4; ++n) acc[m][n] = zero;

    for (int kt = 0; kt < KDIM; kt += 64) {
        const i32x4 a0 = *(const i32x4*)(Aq + a_base + kt);
        const i32x4 a1 = *(const i32x4*)(Aq + a_base + (size_t)64 * KDIM + kt);
        const i32x4 b0 = *(const i32x4*)(Bq + b_base + kt);
        const i32x4 b1 = *(const i32x4*)(Bq + b_base + (size_t)64 * KDIM + kt);
        __syncthreads();
        *(i32x4*)(&As[srow * 80 + scol]) = a0;
        *(i32x4*)(&As[(srow + 64) * 80 + scol]) = a1;
        *(i32x4*)(&Bs[srow * 80 + scol]) = b0;
        *(i32x4*)(&Bs[(srow + 64) * 80 + scol]) = b1;
        __syncthreads();

        i32x4 af[4], bf[4];
        #pragma unroll
        for (int m = 0; m < 4; ++m)
            af[m] = *(const i32x4*)(&As[(wm + m * 16 + l15) * 80 + l16 * 16]);
        #pragma unroll
        for (int n = 0; n < 4; ++n)
            bf[n] = *(const i32x4*)(&Bs[(wn + n * 16 + l15) * 80 + l16 * 16]);

        #pragma unroll
        for (int m = 0; m < 4; ++m)
            #pragma unroll
            for (int n = 0; n < 4; ++n)
                acc[m][n] = __builtin_amdgcn_mfma_i32_16x16x64_i8(
                                af[m], bf[n], acc[m][n], 0, 0, 0);
    }

    #pragma unroll
    for (int m = 0; m < 4; ++m) {
        #pragma unroll
        for (int n = 0; n < 4; ++n) {
            const int col = col0 + wn + n * 16 + l15;
            const float sw = scale_w[col];
            const float bv = bias[col];
            #pragma unroll
            for (int r = 0; r < 4; ++r) {
                const int row = row0 + wm + m * 16 + l16 * 4 + r;
                const float sx = scale_x[row];
                out[(size_t)row * NDIM + col] =
                    (float)acc[m][n][r] * sx * sw + bv;
            }
        }
    }
}

// ---------------------------------------------------------------------------
extern "C" void kernel_launch(void* const* d_in, const int* in_sizes, int n_in,
                              void* d_out, int out_size, void* d_ws, size_t ws_size,
                              hipStream_t stream)
{
    const float* x        = (const float*)d_in[0];
    const int*   Wq       = (const int*)d_in[1];
    const float* scale    = (const float*)d_in[2];
    const float* zp       = (const float*)d_in[3];
    const float* svd_up   = (const float*)d_in[4];
    const float* svd_down = (const float*)d_in[5];
    const float* bias     = (const float*)d_in[6];
    float* out = (float*)d_out;

    // ws layout: xq 16MB | wq 16MB | scale_x 16KB | scale_w 16KB | partial 64KB
    int8_t* xq = (int8_t*)d_ws;
    int8_t* wq = (int8_t*)d_ws + ((size_t)16 << 20);
    float* scale_x = (float*)((char*)d_ws + ((size_t)32 << 20));
    float* scale_w = scale_x + TDIM;
    float* partial_max = scale_w + NDIM;

    // d_out doubles as fp32 Wf scratch (64MB) — fully overwritten by the GEMM.
    float* Wf = out;

    quant_x_kernel<<<TDIM, 256, 0, stream>>>(x, xq, scale_x);
    w_pass1_kernel<<<dim3(NDIM / 16, NCHUNK), 256, 0, stream>>>(
        Wq, scale, zp, svd_up, svd_down, Wf, partial_max);
    finalize_sw_kernel<<<NDIM / 256, 256, 0, stream>>>(partial_max, scale_w);
    w_quant_kernel<<<(size_t)NDIM * KDIM / (256 * 4), 256, 0, stream>>>(Wf, scale_w, wq);
    gemm_i8_kernel<<<(TDIM / 128) * (NDIM / 128), 256, 0, stream>>>(
        xq, wq, scale_x, scale_w, bias, out);
}

// Round 3
// 184.619 us; speedup vs baseline: 1.4867x; 1.1788x over previous
//
#include <hip/hip_runtime.h>
#include <stdint.h>

#define TDIM 4096   // tokens = 2*2048
#define KDIM 4096   // IN_F
#define NDIM 4096   // OUT_F
#define RANK 128
#define NG   32
#define NCHUNK 4    // col-chunks in w_pass1 (1024 cols each)

typedef __attribute__((ext_vector_type(4))) int i32x4;

__device__ inline void fma4(float4& a, float s, const float4& b) {
    a.x = fmaf(s, b.x, a.x);
    a.y = fmaf(s, b.y, a.y);
    a.z = fmaf(s, b.z, a.z);
    a.w = fmaf(s, b.w, a.w);
}

// ---------------------------------------------------------------------------
// Kernel 1: per-token activation quantization (unchanged from R1).
// ---------------------------------------------------------------------------
__global__ __launch_bounds__(256) void quant_x_kernel(
    const float* __restrict__ x, int8_t* __restrict__ xq,
    float* __restrict__ scale_x)
{
    const int row = blockIdx.x;
    const float* xr = x + (size_t)row * KDIM;
    __shared__ float buf[KDIM];
    __shared__ float wred[4];

    float m = 0.f;
    for (int j = threadIdx.x; j < KDIM; j += 256) {
        float v = xr[j];
        buf[j] = v;
        m = fmaxf(m, fabsf(v));
    }
    #pragma unroll
    for (int off = 32; off > 0; off >>= 1)
        m = fmaxf(m, __shfl_xor(m, off, 64));
    if ((threadIdx.x & 63) == 0) wred[threadIdx.x >> 6] = m;
    __syncthreads();
    const float mt = fmaxf(fmaxf(wred[0], wred[1]), fmaxf(wred[2], wred[3]));
    const float sx = mt / 127.0f;
    if (threadIdx.x == 0) scale_x[row] = sx;

    for (int j = threadIdx.x; j < KDIM; j += 256) {
        float q = rintf(buf[j] / sx);
        q = fminf(fmaxf(q, -128.f), 127.f);
        xq[(size_t)row * KDIM + j] = (int8_t)q;
    }
}

// ---------------------------------------------------------------------------
// Kernel 2: W dequant + SVD correction -> Wf + per-(row,chunk) partial max.
// (unchanged from R1 — grid (256,4))
// ---------------------------------------------------------------------------
__global__ __launch_bounds__(256) void w_pass1_kernel(
    const int* __restrict__ Wq, const float* __restrict__ scale,
    const float* __restrict__ zp, const float* __restrict__ svd_up,
    const float* __restrict__ svd_down,
    float* __restrict__ Wf, float* __restrict__ partial_max)
{
    const int o0 = blockIdx.x * 16;
    const int chunk = blockIdx.y;
    const int i = chunk * 1024 + threadIdx.x * 4;
    __shared__ __align__(16) float up_s[16][RANK];
    __shared__ float red[16][4];

    for (int idx = threadIdx.x; idx < 16 * RANK; idx += 256)
        up_s[idx >> 7][idx & 127] = svd_up[(size_t)o0 * RANK + idx];
    __syncthreads();

    float4 sv[16];
    #pragma unroll
    for (int m = 0; m < 16; ++m) sv[m] = make_float4(0.f, 0.f, 0.f, 0.f);

    for (int r4 = 0; r4 < RANK; r4 += 4) {
        const float4 d0 = *(const float4*)(svd_down + (size_t)(r4 + 0) * KDIM + i);
        const float4 d1 = *(const float4*)(svd_down + (size_t)(r4 + 1) * KDIM + i);
        const float4 d2 = *(const float4*)(svd_down + (size_t)(r4 + 2) * KDIM + i);
        const float4 d3 = *(const float4*)(svd_down + (size_t)(r4 + 3) * KDIM + i);
        #pragma unroll
        for (int m = 0; m < 16; ++m) {
            const float4 u = *(const float4*)(&up_s[m][r4]);
            fma4(sv[m], u.x, d0);
            fma4(sv[m], u.y, d1);
            fma4(sv[m], u.z, d2);
            fma4(sv[m], u.w, d3);
        }
    }

    const int g = i >> 7;
    float rmax[16];
    #pragma unroll
    for (int m = 0; m < 16; ++m) {
        const int o = o0 + m;
        const int4 q4 = *(const int4*)(Wq + (size_t)o * KDIM + i);
        const float s = scale[o * NG + g];
        const float z = zp[o * NG + g];
        float4 wf;
        wf.x = ((float)q4.x - z) * s + sv[m].x;
        wf.y = ((float)q4.y - z) * s + sv[m].y;
        wf.z = ((float)q4.z - z) * s + sv[m].z;
        wf.w = ((float)q4.w - z) * s + sv[m].w;
        *(float4*)(Wf + (size_t)o * KDIM + i) = wf;
        rmax[m] = fmaxf(fmaxf(fabsf(wf.x), fabsf(wf.y)),
                        fmaxf(fabsf(wf.z), fabsf(wf.w)));
    }

    const int lane = threadIdx.x & 63, wv = threadIdx.x >> 6;
    #pragma unroll
    for (int m = 0; m < 16; ++m) {
        float v = rmax[m];
        #pragma unroll
        for (int off = 32; off > 0; off >>= 1)
            v = fmaxf(v, __shfl_xor(v, off, 64));
        if (lane == 0) red[m][wv] = v;
    }
    __syncthreads();
    if (threadIdx.x < 16) {
        const float v = fmaxf(fmaxf(red[threadIdx.x][0], red[threadIdx.x][1]),
                              fmaxf(red[threadIdx.x][2], red[threadIdx.x][3]));
        partial_max[(size_t)(o0 + threadIdx.x) * NCHUNK + chunk] = v;
    }
}

__global__ __launch_bounds__(256) void finalize_sw_kernel(
    const float* __restrict__ partial_max, float* __restrict__ scale_w)
{
    const int o = blockIdx.x * 256 + threadIdx.x;
    const float* p = partial_max + (size_t)o * NCHUNK;
    scale_w[o] = fmaxf(fmaxf(p[0], p[1]), fmaxf(p[2], p[3])) / 127.0f;
}

__global__ __launch_bounds__(256) void w_quant_kernel(
    const float* __restrict__ Wf, const float* __restrict__ scale_w,
    int8_t* __restrict__ wq)
{
    const size_t idx = ((size_t)blockIdx.x * 256 + threadIdx.x) * 4;
    const int o = (int)(idx >> 12);
    const float sw = scale_w[o];
    const float4 wf = *(const float4*)(Wf + idx);
    char4 q;
    q.x = (char)fminf(fmaxf(rintf(wf.x / sw), -128.f), 127.f);
    q.y = (char)fminf(fmaxf(rintf(wf.y / sw), -128.f), 127.f);
    q.z = (char)fminf(fmaxf(rintf(wf.z / sw), -128.f), 127.f);
    q.w = (char)fminf(fmaxf(rintf(wf.w / sw), -128.f), 127.f);
    *(char4*)(wq + idx) = q;
}

// ---------------------------------------------------------------------------
// Kernel 4: int8 GEMM, 256x256 tile, BK=64, 8 waves (2Mx4N), 8-phase schedule
// (T3+T4 counted-vmcnt + T5 setprio + T1 XCD swizzle), global_load_lds direct
// staging, double-buffered LDS (64KB).
//
// Per iteration: 2 K-tiles (T=2i from buf0, T+1 from buf1), 8 phases.
// Stage choreography (region R staged >=1 phase after its last read; reads
// complete before each phase-end barrier via compiler lgkmcnt before MFMA):
//   buf B last read ph2/ph6; buf A last read ph3/ph7.
//   ph1: buf1.A-h1<-2i+1  ph2: buf1.B-h1<-2i+1  ph3: buf0.B-h0<-2i+2
//   ph4: buf0.A-h0<-2i+2 +vmcnt(2)   ph5: buf0.A-h1<-2i+2
//   ph6: buf0.B-h1<-2i+2  ph7: buf1.B-h0<-2i+3  ph8: buf1.A-h0<-2i+3 +vmcnt(2)
// vmcnt(2)@ph4 completes {prev ph7,8, ph1,2} = all of tile 2i+1 before ph5
// reads buf1; vmcnt(2)@ph8 completes ph3-6 = tile 2i+2 before next ph1.
// Tail: kt clamped to 63 (dummy re-stages keep vmcnt counts uniform).
// Bank notes: 64B LDS rows -> frag reads are bank-uniform (8 lanes per
// 4-bank group = b128 minimum) -> no swizzle needed; gload_lds dest linear.
// ---------------------------------------------------------------------------
__global__ __launch_bounds__(512, 2) void gemm_i8_kernel(
    const int8_t* __restrict__ Aq,   // [T][K]
    const int8_t* __restrict__ Bq,   // [N][K]
    const float* __restrict__ scale_x, const float* __restrict__ scale_w,
    const float* __restrict__ bias, float* __restrict__ out)
{
    __shared__ __align__(16) int8_t lds[65536];
    // A: db*16384 + h*8192 (halves = 128 rows x 64B); B: +32768 same layout.

    const int tid  = threadIdx.x;
    const int lane = tid & 63;
    const int wid  = tid >> 6;          // 0..7
    const int wmp  = wid >> 2;          // 0..1  (M wave)
    const int wnp  = wid & 3;           // 0..3  (N wave)
    const int l15  = lane & 15, l16 = lane >> 4;

    // T1: bijective XCD swizzle (256 blocks % 8 == 0)
    const int swz  = (blockIdx.x & 7) * 32 + (blockIdx.x >> 3);
    const int row0 = (swz >> 4) * 256;
    const int col0 = (swz & 15) * 256;

    // staging: one gload_lds per thread per half-tile (512 x 16B = 8KB)
    const int srow = wid * 16 + (lane >> 2);      // 0..127 within half
    const int scol = (lane & 3) * 16;             // 0..48
    const int8_t* const A0 = Aq + (size_t)(row0 + srow) * KDIM + scol;
    const int8_t* const B0 = Bq + (size_t)(col0 + srow) * KDIM + scol;
    int8_t* const ldsw = lds + wid * 1024;        // wave-uniform dest base

#define STAGE_A(db, h, kt) \
    __builtin_amdgcn_global_load_lds( \
        (const __attribute__((address_space(1))) void*)(A0 + (size_t)(h) * 128 * KDIM + (kt) * 64), \
        (__attribute__((address_space(3))) void*)(ldsw + (db) * 16384 + (h) * 8192), 16, 0, 0)
#define STAGE_B(db, h, kt) \
    __builtin_amdgcn_global_load_lds( \
        (const __attribute__((address_space(1))) void*)(B0 + (size_t)(h) * 128 * KDIM + (kt) * 64), \
        (__attribute__((address_space(3))) void*)(ldsw + 32768 + (db) * 16384 + (h) * 8192), 16, 0, 0)

    // fragment read bases (A half = wmp; B half = wnp>>1)
    const int aoff = wmp * 8192 + l15 * 64 + l16 * 16;
    const int boff = 32768 + (wnp >> 1) * 8192 + (wnp & 1) * 4096 + l15 * 64 + l16 * 16;

    i32x4 Ar[4], Br[2][2];
    i32x4 acc[8][4];
    #pragma unroll
    for (int m = 0; m < 8; ++m)
        #pragma unroll
        for (int n = 0; n < 4; ++n) acc[m][n] = (i32x4){0, 0, 0, 0};

#define LDA(db, qm) { const int8_t* p = lds + (db) * 16384 + aoff + (qm) * 4096; \
    Ar[0] = *(const i32x4*)(p);        Ar[1] = *(const i32x4*)(p + 1024); \
    Ar[2] = *(const i32x4*)(p + 2048); Ar[3] = *(const i32x4*)(p + 3072); }
#define LDB(db, qn) { const int8_t* p = lds + (db) * 16384 + boff + (qn) * 2048; \
    Br[qn][0] = *(const i32x4*)(p);    Br[qn][1] = *(const i32x4*)(p + 1024); }
#define MMA(qm, qn) { \
    _Pragma("unroll") for (int fm = 0; fm < 4; ++fm) \
    _Pragma("unroll") for (int fn = 0; fn < 2; ++fn) \
        acc[(qm) * 4 + fm][(qn) * 2 + fn] = __builtin_amdgcn_mfma_i32_16x16x64_i8( \
            Ar[fm], Br[qn][fn], acc[(qm) * 4 + fm][(qn) * 2 + fn], 0, 0, 0); }

#define FENCE asm volatile("" ::: "memory")
#define BAR   __builtin_amdgcn_s_barrier()
#define VMCNT2 asm volatile("s_waitcnt vmcnt(2)" ::: "memory")
#define PRIO1 __builtin_amdgcn_s_setprio(1)
#define PRIO0 __builtin_amdgcn_s_setprio(0)

    // prologue: tile0 (all 4 halves) -> buf0; tile1 {B-h0, A-h0} -> buf1
    STAGE_A(0, 0, 0); STAGE_A(0, 1, 0); STAGE_B(0, 0, 0); STAGE_B(0, 1, 0);
    STAGE_B(1, 0, 1); STAGE_A(1, 0, 1);
    VMCNT2;           // tile0 complete; {B1h0,A1h0} stay in flight
    BAR;

    for (int i = 0; i < 32; ++i) {
        const int kt1 = 2 * i + 1;
        const int kt2 = (2 * i + 2 > 63) ? 63 : 2 * i + 2;
        const int kt3 = (2 * i + 3 > 63) ? 63 : 2 * i + 3;

        // ---- tile T = 2i from buf0 ----
        LDA(0, 0); LDB(0, 0); FENCE; STAGE_A(1, 1, kt1);
        BAR; PRIO1; MMA(0, 0); PRIO0; BAR;                 // ph1

        LDB(0, 1); FENCE; STAGE_B(1, 1, kt1);
        BAR; PRIO1; MMA(0, 1); PRIO0; BAR;                 // ph2

        LDA(0, 1); FENCE; STAGE_B(0, 0, kt2);
        BAR; PRIO1; MMA(1, 0); PRIO0; BAR;                 // ph3

        FENCE; STAGE_A(0, 0, kt2); VMCNT2;
        BAR; PRIO1; MMA(1, 1); PRIO0; BAR;                 // ph4

        // ---- tile T+1 = 2i+1 from buf1 ----
        LDA(1, 0); LDB(1, 0); FENCE; STAGE_A(0, 1, kt2);
        BAR; PRIO1; MMA(0, 0); PRIO0; BAR;                 // ph5

        LDB(1, 1); FENCE; STAGE_B(0, 1, kt2);
        BAR; PRIO1; MMA(0, 1); PRIO0; BAR;                 // ph6

        LDA(1, 1); FENCE; STAGE_B(1, 0, kt3);
        BAR; PRIO1; MMA(1, 0); PRIO0; BAR;                 // ph7

        FENCE; STAGE_A(1, 0, kt3); VMCNT2;
        BAR; PRIO1; MMA(1, 1); PRIO0; BAR;                 // ph8
    }

    // epilogue: C/D layout col = lane&15, row = (lane>>4)*4 + reg
    const int orow0 = row0 + wmp * 128;
    const int ocol0 = col0 + wnp * 64;
    #pragma unroll
    for (int fn = 0; fn < 4; ++fn) {
        const int col = ocol0 + fn * 16 + l15;
        const float sw = scale_w[col];
        const float bv = bias[col];
        #pragma unroll
        for (int fm = 0; fm < 8; ++fm) {
            #pragma unroll
            for (int j = 0; j < 4; ++j) {
                const int row = orow0 + fm * 16 + l16 * 4 + j;
                out[(size_t)row * NDIM + col] =
                    (float)acc[fm][fn][j] * scale_x[row] * sw + bv;
            }
        }
    }
#undef STAGE_A
#undef STAGE_B
#undef LDA
#undef LDB
#undef MMA
#undef FENCE
#undef BAR
#undef VMCNT2
#undef PRIO1
#undef PRIO0
}

// ---------------------------------------------------------------------------
extern "C" void kernel_launch(void* const* d_in, const int* in_sizes, int n_in,
                              void* d_out, int out_size, void* d_ws, size_t ws_size,
                              hipStream_t stream)
{
    const float* x        = (const float*)d_in[0];
    const int*   Wq       = (const int*)d_in[1];
    const float* scale    = (const float*)d_in[2];
    const float* zp       = (const float*)d_in[3];
    const float* svd_up   = (const float*)d_in[4];
    const float* svd_down = (const float*)d_in[5];
    const float* bias     = (const float*)d_in[6];
    float* out = (float*)d_out;

    // ws layout: xq 16MB | wq 16MB | scale_x 16KB | scale_w 16KB | partial 64KB
    int8_t* xq = (int8_t*)d_ws;
    int8_t* wq = (int8_t*)d_ws + ((size_t)16 << 20);
    float* scale_x = (float*)((char*)d_ws + ((size_t)32 << 20));
    float* scale_w = scale_x + TDIM;
    float* partial_max = scale_w + NDIM;

    // d_out doubles as fp32 Wf scratch (64MB) — fully overwritten by the GEMM.
    float* Wf = out;

    quant_x_kernel<<<TDIM, 256, 0, stream>>>(x, xq, scale_x);
    w_pass1_kernel<<<dim3(NDIM / 16, NCHUNK), 256, 0, stream>>>(
        Wq, scale, zp, svd_up, svd_down, Wf, partial_max);
    finalize_sw_kernel<<<NDIM / 256, 256, 0, stream>>>(partial_max, scale_w);
    w_quant_kernel<<<(size_t)NDIM * KDIM / (256 * 4), 256, 0, stream>>>(Wf, scale_w, wq);
    gemm_i8_kernel<<<(TDIM / 256) * (NDIM / 256), 512, 0, stream>>>(
        xq, wq, scale_x, scale_w, bias, out);
}

// Round 4
// 159.056 us; speedup vs baseline: 1.7256x; 1.1607x over previous
//
#include <hip/hip_runtime.h>
#include <stdint.h>

#define TDIM 4096   // tokens = 2*2048
#define KDIM 4096   // IN_F
#define NDIM 4096   // OUT_F
#define RANK 128
#define NG   32
#define NCHUNK 64   // per-64-col partial-max chunks (one per wave-col-strip)

typedef __attribute__((ext_vector_type(4))) int   i32x4;
typedef __attribute__((ext_vector_type(4))) float f32x4;
typedef __attribute__((ext_vector_type(8))) short short8;

__device__ inline unsigned short f2bf(float f) {   // f32 -> bf16 RNE
    union { float f; unsigned u; } v; v.f = f;
    const unsigned r = v.u + 0x7FFF + ((v.u >> 16) & 1);
    return (unsigned short)(r >> 16);
}

// ---------------------------------------------------------------------------
// Kernel 1: per-token activation quantization (unchanged).
// ---------------------------------------------------------------------------
__global__ __launch_bounds__(256) void quant_x_kernel(
    const float* __restrict__ x, int8_t* __restrict__ xq,
    float* __restrict__ scale_x)
{
    const int row = blockIdx.x;
    const float* xr = x + (size_t)row * KDIM;
    __shared__ float buf[KDIM];
    __shared__ float wred[4];

    float m = 0.f;
    for (int j = threadIdx.x; j < KDIM; j += 256) {
        float v = xr[j];
        buf[j] = v;
        m = fmaxf(m, fabsf(v));
    }
    #pragma unroll
    for (int off = 32; off > 0; off >>= 1)
        m = fmaxf(m, __shfl_xor(m, off, 64));
    if ((threadIdx.x & 63) == 0) wred[threadIdx.x >> 6] = m;
    __syncthreads();
    const float mt = fmaxf(fmaxf(wred[0], wred[1]), fmaxf(wred[2], wred[3]));
    const float sx = mt / 127.0f;
    if (threadIdx.x == 0) scale_x[row] = sx;

    for (int j = threadIdx.x; j < KDIM; j += 256) {
        float q = rintf(buf[j] / sx);
        q = fminf(fmaxf(q, -128.f), 127.f);
        xq[(size_t)row * KDIM + j] = (int8_t)q;
    }
}

// ---------------------------------------------------------------------------
// Kernel 1b: convert svd factors to bf16 for MFMA.
//   blocks 0..255  : dnt[i][k] = bf16(svd_down[k][i])   (transpose, [4096][128])
//   blocks 256..383: upb[o][k] = bf16(svd_up[o][k])     (same layout, [4096][128])
// 3 MB total output; one-time, L2-resident afterwards.
// ---------------------------------------------------------------------------
typedef __attribute__((ext_vector_type(8))) unsigned short u16x8;

__global__ __launch_bounds__(256) void conv_svd_kernel(
    const float* __restrict__ svd_up, const float* __restrict__ svd_down,
    unsigned short* __restrict__ upb, unsigned short* __restrict__ dnt)
{
    const int b = blockIdx.x;
    if (b < 256) {
        const int t = b * 256 + threadIdx.x;   // 65536 chunk-threads
        const int i  = t >> 4;                 // col 0..4095
        const int k0 = (t & 15) * 8;
        u16x8 v;
        #pragma unroll
        for (int j = 0; j < 8; ++j)
            v[j] = f2bf(svd_down[(size_t)(k0 + j) * KDIM + i]);
        *(u16x8*)(dnt + (size_t)i * RANK + k0) = v;
    } else {
        const int t = (b - 256) * 256 + threadIdx.x;   // 32768 threads x 16 elems
        const float4* src = (const float4*)svd_up + (size_t)t * 4;
        #pragma unroll
        for (int h = 0; h < 2; ++h) {
            const float4 a = src[h * 2], c = src[h * 2 + 1];
            u16x8 v;
            v[0] = f2bf(a.x); v[1] = f2bf(a.y); v[2] = f2bf(a.z); v[3] = f2bf(a.w);
            v[4] = f2bf(c.x); v[5] = f2bf(c.y); v[6] = f2bf(c.z); v[7] = f2bf(c.w);
            *(u16x8*)(upb + (size_t)t * 16 + h * 8) = v;
        }
    }
}

// ---------------------------------------------------------------------------
// Kernel 2: W dequant via bf16 MFMA correction.
// corr = up[rows,128] x down_T[cols,128]^T  (16x16x32 bf16, K=128 = 4 steps,
// no LDS: both operands L2-resident, frags contiguous 16B/lane).
// Wf = (Wq - zp)*scale + corr  -> d_out scratch; per-(row,64-col) max -> partial.
// Block 256 thr = 4 waves (2M x 2N); tile 64 rows x 128 cols; grid (64,32).
// ---------------------------------------------------------------------------
__global__ __launch_bounds__(256) void w_pass1_mfma_kernel(
    const int* __restrict__ Wq, const float* __restrict__ scale,
    const float* __restrict__ zp,
    const unsigned short* __restrict__ upb,   // [4096][128] bf16
    const unsigned short* __restrict__ dnt,   // [4096][128] bf16 (down^T)
    float* __restrict__ Wf, float* __restrict__ partial_max)
{
    const int lane = threadIdx.x & 63, wid = threadIdx.x >> 6;
    const int wm = wid >> 1, wn = wid & 1;
    const int l15 = lane & 15, l16 = lane >> 4;
    const int row0 = blockIdx.x * 64 + wm * 32;
    const int col0 = blockIdx.y * 128 + wn * 64;

    // A frags: up rows; B frags: down_T rows (=cols). 8 bf16 (16B) per lane:
    // row/col = l&15, k = kk*32 + (l>>4)*8   (layout validated by the i8 GEMM)
    short8 af[2][4], bfr[4][4];
    #pragma unroll
    for (int mi = 0; mi < 2; ++mi)
        #pragma unroll
        for (int kk = 0; kk < 4; ++kk)
            af[mi][kk] = *(const short8*)(upb +
                (size_t)(row0 + mi * 16 + l15) * RANK + kk * 32 + l16 * 8);
    #pragma unroll
    for (int ni = 0; ni < 4; ++ni)
        #pragma unroll
        for (int kk = 0; kk < 4; ++kk)
            bfr[ni][kk] = *(const short8*)(dnt +
                (size_t)(col0 + ni * 16 + l15) * RANK + kk * 32 + l16 * 8);

    f32x4 acc[2][4];
    #pragma unroll
    for (int mi = 0; mi < 2; ++mi)
        #pragma unroll
        for (int ni = 0; ni < 4; ++ni) acc[mi][ni] = (f32x4){0.f, 0.f, 0.f, 0.f};

    #pragma unroll
    for (int kk = 0; kk < 4; ++kk)
        #pragma unroll
        for (int mi = 0; mi < 2; ++mi)
            #pragma unroll
            for (int ni = 0; ni < 4; ++ni)
                acc[mi][ni] = __builtin_amdgcn_mfma_f32_16x16x32_bf16(
                    af[mi][kk], bfr[ni][kk], acc[mi][ni], 0, 0, 0);

    // epilogue: dequant + store + per-row |max|
    float rmax[2][4];
    #pragma unroll
    for (int mi = 0; mi < 2; ++mi)
        #pragma unroll
        for (int j = 0; j < 4; ++j) rmax[mi][j] = 0.f;

    #pragma unroll
    for (int ni = 0; ni < 4; ++ni) {
        const int col = col0 + ni * 16 + l15;
        const int g = col >> 7;
        #pragma unroll
        for (int mi = 0; mi < 2; ++mi) {
            #pragma unroll
            for (int j = 0; j < 4; ++j) {
                const int row = row0 + mi * 16 + l16 * 4 + j;
                const float s = scale[row * NG + g];
                const float z = zp[row * NG + g];
                const float q = (float)Wq[(size_t)row * KDIM + col];
                const float wf = (q - z) * s + acc[mi][ni][j];
                Wf[(size_t)row * KDIM + col] = wf;
                rmax[mi][j] = fmaxf(rmax[mi][j], fabsf(wf));
            }
        }
    }

    // lanes 0..15 of each l16-group share rows; xor-reduce over low 4 bits
    #pragma unroll
    for (int mi = 0; mi < 2; ++mi) {
        #pragma unroll
        for (int j = 0; j < 4; ++j) {
            float v = rmax[mi][j];
            v = fmaxf(v, __shfl_xor(v, 1, 64));
            v = fmaxf(v, __shfl_xor(v, 2, 64));
            v = fmaxf(v, __shfl_xor(v, 4, 64));
            v = fmaxf(v, __shfl_xor(v, 8, 64));
            if (l15 == 0) {
                const int row = row0 + mi * 16 + l16 * 4 + j;
                partial_max[(size_t)row * NCHUNK + blockIdx.y * 2 + wn] = v;
            }
        }
    }
}

// ---------------------------------------------------------------------------
// Kernel 2b: reduce 64 per-chunk partial maxes -> scale_w.
// ---------------------------------------------------------------------------
__global__ __launch_bounds__(256) void finalize_sw_kernel(
    const float* __restrict__ partial_max, float* __restrict__ scale_w)
{
    const int o = blockIdx.x * 256 + threadIdx.x;
    const float4* p = (const float4*)(partial_max + (size_t)o * NCHUNK);
    float m = 0.f;
    #pragma unroll
    for (int i = 0; i < NCHUNK / 4; ++i) {
        const float4 v = p[i];
        m = fmaxf(m, fmaxf(fmaxf(v.x, v.y), fmaxf(v.z, v.w)));
    }
    scale_w[o] = m / 127.0f;
}

// ---------------------------------------------------------------------------
// Kernel 3: quantize Wf -> w_q int8 [out][in] (unchanged).
// ---------------------------------------------------------------------------
__global__ __launch_bounds__(256) void w_quant_kernel(
    const float* __restrict__ Wf, const float* __restrict__ scale_w,
    int8_t* __restrict__ wq)
{
    const size_t idx = ((size_t)blockIdx.x * 256 + threadIdx.x) * 4;
    const int o = (int)(idx >> 12);
    const float sw = scale_w[o];
    const float4 wf = *(const float4*)(Wf + idx);
    char4 q;
    q.x = (char)fminf(fmaxf(rintf(wf.x / sw), -128.f), 127.f);
    q.y = (char)fminf(fmaxf(rintf(wf.y / sw), -128.f), 127.f);
    q.z = (char)fminf(fmaxf(rintf(wf.z / sw), -128.f), 127.f);
    q.w = (char)fminf(fmaxf(rintf(wf.w / sw), -128.f), 127.f);
    *(char4*)(wq + idx) = q;
}

// ---------------------------------------------------------------------------
// Kernel 4: int8 GEMM, 256x256 tile, BK=64, 8 waves, 8-phase counted-vmcnt
// schedule + setprio + XCD swizzle, global_load_lds staging (unchanged, R2).
// ---------------------------------------------------------------------------
__global__ __launch_bounds__(512, 2) void gemm_i8_kernel(
    const int8_t* __restrict__ Aq,   // [T][K]
    const int8_t* __restrict__ Bq,   // [N][K]
    const float* __restrict__ scale_x, const float* __restrict__ scale_w,
    const float* __restrict__ bias, float* __restrict__ out)
{
    __shared__ __align__(16) int8_t lds[65536];

    const int tid  = threadIdx.x;
    const int lane = tid & 63;
    const int wid  = tid >> 6;
    const int wmp  = wid >> 2;
    const int wnp  = wid & 3;
    const int l15  = lane & 15, l16 = lane >> 4;

    const int swz  = (blockIdx.x & 7) * 32 + (blockIdx.x >> 3);
    const int row0 = (swz >> 4) * 256;
    const int col0 = (swz & 15) * 256;

    const int srow = wid * 16 + (lane >> 2);
    const int scol = (lane & 3) * 16;
    const int8_t* const A0 = Aq + (size_t)(row0 + srow) * KDIM + scol;
    const int8_t* const B0 = Bq + (size_t)(col0 + srow) * KDIM + scol;
    int8_t* const ldsw = lds + wid * 1024;

#define STAGE_A(db, h, kt) \
    __builtin_amdgcn_global_load_lds( \
        (const __attribute__((address_space(1))) void*)(A0 + (size_t)(h) * 128 * KDIM + (kt) * 64), \
        (__attribute__((address_space(3))) void*)(ldsw + (db) * 16384 + (h) * 8192), 16, 0, 0)
#define STAGE_B(db, h, kt) \
    __builtin_amdgcn_global_load_lds( \
        (const __attribute__((address_space(1))) void*)(B0 + (size_t)(h) * 128 * KDIM + (kt) * 64), \
        (__attribute__((address_space(3))) void*)(ldsw + 32768 + (db) * 16384 + (h) * 8192), 16, 0, 0)

    const int aoff = wmp * 8192 + l15 * 64 + l16 * 16;
    const int boff = 32768 + (wnp >> 1) * 8192 + (wnp & 1) * 4096 + l15 * 64 + l16 * 16;

    i32x4 Ar[4], Br[2][2];
    i32x4 acc[8][4];
    #pragma unroll
    for (int m = 0; m < 8; ++m)
        #pragma unroll
        for (int n = 0; n < 4; ++n) acc[m][n] = (i32x4){0, 0, 0, 0};

#define LDA(db, qm) { const int8_t* p = lds + (db) * 16384 + aoff + (qm) * 4096; \
    Ar[0] = *(const i32x4*)(p);        Ar[1] = *(const i32x4*)(p + 1024); \
    Ar[2] = *(const i32x4*)(p + 2048); Ar[3] = *(const i32x4*)(p + 3072); }
#define LDB(db, qn) { const int8_t* p = lds + (db) * 16384 + boff + (qn) * 2048; \
    Br[qn][0] = *(const i32x4*)(p);    Br[qn][1] = *(const i32x4*)(p + 1024); }
#define MMA(qm, qn) { \
    _Pragma("unroll") for (int fm = 0; fm < 4; ++fm) \
    _Pragma("unroll") for (int fn = 0; fn < 2; ++fn) \
        acc[(qm) * 4 + fm][(qn) * 2 + fn] = __builtin_amdgcn_mfma_i32_16x16x64_i8( \
            Ar[fm], Br[qn][fn], acc[(qm) * 4 + fm][(qn) * 2 + fn], 0, 0, 0); }

#define FENCE asm volatile("" ::: "memory")
#define BAR   __builtin_amdgcn_s_barrier()
#define VMCNT2 asm volatile("s_waitcnt vmcnt(2)" ::: "memory")
#define PRIO1 __builtin_amdgcn_s_setprio(1)
#define PRIO0 __builtin_amdgcn_s_setprio(0)

    STAGE_A(0, 0, 0); STAGE_A(0, 1, 0); STAGE_B(0, 0, 0); STAGE_B(0, 1, 0);
    STAGE_B(1, 0, 1); STAGE_A(1, 0, 1);
    VMCNT2;
    BAR;

    for (int i = 0; i < 32; ++i) {
        const int kt1 = 2 * i + 1;
        const int kt2 = (2 * i + 2 > 63) ? 63 : 2 * i + 2;
        const int kt3 = (2 * i + 3 > 63) ? 63 : 2 * i + 3;

        LDA(0, 0); LDB(0, 0); FENCE; STAGE_A(1, 1, kt1);
        BAR; PRIO1; MMA(0, 0); PRIO0; BAR;                 // ph1

        LDB(0, 1); FENCE; STAGE_B(1, 1, kt1);
        BAR; PRIO1; MMA(0, 1); PRIO0; BAR;                 // ph2

        LDA(0, 1); FENCE; STAGE_B(0, 0, kt2);
        BAR; PRIO1; MMA(1, 0); PRIO0; BAR;                 // ph3

        FENCE; STAGE_A(0, 0, kt2); VMCNT2;
        BAR; PRIO1; MMA(1, 1); PRIO0; BAR;                 // ph4

        LDA(1, 0); LDB(1, 0); FENCE; STAGE_A(0, 1, kt2);
        BAR; PRIO1; MMA(0, 0); PRIO0; BAR;                 // ph5

        LDB(1, 1); FENCE; STAGE_B(0, 1, kt2);
        BAR; PRIO1; MMA(0, 1); PRIO0; BAR;                 // ph6

        LDA(1, 1); FENCE; STAGE_B(1, 0, kt3);
        BAR; PRIO1; MMA(1, 0); PRIO0; BAR;                 // ph7

        FENCE; STAGE_A(1, 0, kt3); VMCNT2;
        BAR; PRIO1; MMA(1, 1); PRIO0; BAR;                 // ph8
    }

    const int orow0 = row0 + wmp * 128;
    const int ocol0 = col0 + wnp * 64;
    #pragma unroll
    for (int fn = 0; fn < 4; ++fn) {
        const int col = ocol0 + fn * 16 + l15;
        const float sw = scale_w[col];
        const float bv = bias[col];
        #pragma unroll
        for (int fm = 0; fm < 8; ++fm) {
            #pragma unroll
            for (int j = 0; j < 4; ++j) {
                const int row = orow0 + fm * 16 + l16 * 4 + j;
                out[(size_t)row * NDIM + col] =
                    (float)acc[fm][fn][j] * scale_x[row] * sw + bv;
            }
        }
    }
#undef STAGE_A
#undef STAGE_B
#undef LDA
#undef LDB
#undef MMA
#undef FENCE
#undef BAR
#undef VMCNT2
#undef PRIO1
#undef PRIO0
}

// ---------------------------------------------------------------------------
extern "C" void kernel_launch(void* const* d_in, const int* in_sizes, int n_in,
                              void* d_out, int out_size, void* d_ws, size_t ws_size,
                              hipStream_t stream)
{
    const float* x        = (const float*)d_in[0];
    const int*   Wq       = (const int*)d_in[1];
    const float* scale    = (const float*)d_in[2];
    const float* zp       = (const float*)d_in[3];
    const float* svd_up   = (const float*)d_in[4];
    const float* svd_down = (const float*)d_in[5];
    const float* bias     = (const float*)d_in[6];
    float* out = (float*)d_out;

    // ws: xq 16MB | wq 16MB | scale_x 16KB | scale_w 16KB | partial 1MB |
    //     upb 1MB | dnt 1MB
    int8_t* xq = (int8_t*)d_ws;
    int8_t* wq = (int8_t*)d_ws + ((size_t)16 << 20);
    float* scale_x = (float*)((char*)d_ws + ((size_t)32 << 20));
    float* scale_w = scale_x + TDIM;
    float* partial_max = scale_w + NDIM;                       // 4096*64*4 = 1MB
    unsigned short* upb = (unsigned short*)(partial_max + (size_t)NDIM * NCHUNK);
    unsigned short* dnt = upb + (size_t)NDIM * RANK;

    // d_out doubles as fp32 Wf scratch (64MB) — fully overwritten by the GEMM.
    float* Wf = out;

    quant_x_kernel<<<TDIM, 256, 0, stream>>>(x, xq, scale_x);
    conv_svd_kernel<<<384, 256, 0, stream>>>(svd_up, svd_down, upb, dnt);
    w_pass1_mfma_kernel<<<dim3(NDIM / 64, KDIM / 128), 256, 0, stream>>>(
        Wq, scale, zp, upb, dnt, Wf, partial_max);
    finalize_sw_kernel<<<NDIM / 256, 256, 0, stream>>>(partial_max, scale_w);
    w_quant_kernel<<<(size_t)NDIM * KDIM / (256 * 4), 256, 0, stream>>>(Wf, scale_w, wq);
    gemm_i8_kernel<<<(TDIM / 256) * (NDIM / 256), 512, 0, stream>>>(
        xq, wq, scale_x, scale_w, bias, out);
}

// Round 5
// 155.187 us; speedup vs baseline: 1.7687x; 1.0249x over previous
//
#include <hip/hip_runtime.h>
#include <stdint.h>

#define TDIM 4096   // tokens = 2*2048
#define KDIM 4096   // IN_F
#define NDIM 4096   // OUT_F
#define RANK 128
#define NG   32
#define NCHUNK 64   // per-64-col partial-max chunks

typedef __attribute__((ext_vector_type(4))) int   i32x4;
typedef __attribute__((ext_vector_type(4))) float f32x4;
typedef __attribute__((ext_vector_type(8))) short short8;
typedef __attribute__((ext_vector_type(8))) unsigned short u16x8;

__device__ inline unsigned short f2bf(float f) {   // f32 -> bf16 RNE
    union { float f; unsigned u; } v; v.f = f;
    const unsigned r = v.u + 0x7FFF + ((v.u >> 16) & 1);
    return (unsigned short)(r >> 16);
}

// ---------------------------------------------------------------------------
// Kernel 1: per-token activation quantization (float4-vectorized).
// ---------------------------------------------------------------------------
__global__ __launch_bounds__(256) void quant_x_kernel(
    const float* __restrict__ x, int8_t* __restrict__ xq,
    float* __restrict__ scale_x)
{
    const int row = blockIdx.x;
    const float4* xr = (const float4*)(x + (size_t)row * KDIM);   // 1024 f4
    __shared__ float4 buf[1024];       // 16 KB
    __shared__ float wred[4];

    float m = 0.f;
    #pragma unroll
    for (int j = 0; j < 4; ++j) {
        const float4 v = xr[threadIdx.x + j * 256];
        buf[threadIdx.x + j * 256] = v;
        m = fmaxf(m, fmaxf(fmaxf(fabsf(v.x), fabsf(v.y)),
                           fmaxf(fabsf(v.z), fabsf(v.w))));
    }
    #pragma unroll
    for (int off = 32; off > 0; off >>= 1)
        m = fmaxf(m, __shfl_xor(m, off, 64));
    if ((threadIdx.x & 63) == 0) wred[threadIdx.x >> 6] = m;
    __syncthreads();
    const float mt = fmaxf(fmaxf(wred[0], wred[1]), fmaxf(wred[2], wred[3]));
    const float sx = mt / 127.0f;
    if (threadIdx.x == 0) scale_x[row] = sx;

    char4* xo = (char4*)(xq + (size_t)row * KDIM);
    #pragma unroll
    for (int j = 0; j < 4; ++j) {
        const float4 v = buf[threadIdx.x + j * 256];
        char4 q;
        q.x = (char)fminf(fmaxf(rintf(v.x / sx), -128.f), 127.f);
        q.y = (char)fminf(fmaxf(rintf(v.y / sx), -128.f), 127.f);
        q.z = (char)fminf(fmaxf(rintf(v.z / sx), -128.f), 127.f);
        q.w = (char)fminf(fmaxf(rintf(v.w / sx), -128.f), 127.f);
        xo[threadIdx.x + j * 256] = q;
    }
}

// ---------------------------------------------------------------------------
// Kernel 1b: convert svd factors to bf16 (unchanged).
// ---------------------------------------------------------------------------
__global__ __launch_bounds__(256) void conv_svd_kernel(
    const float* __restrict__ svd_up, const float* __restrict__ svd_down,
    unsigned short* __restrict__ upb, unsigned short* __restrict__ dnt)
{
    const int b = blockIdx.x;
    if (b < 256) {
        const int t = b * 256 + threadIdx.x;
        const int i  = t >> 4;
        const int k0 = (t & 15) * 8;
        u16x8 v;
        #pragma unroll
        for (int j = 0; j < 8; ++j)
            v[j] = f2bf(svd_down[(size_t)(k0 + j) * KDIM + i]);
        *(u16x8*)(dnt + (size_t)i * RANK + k0) = v;
    } else {
        const int t = (b - 256) * 256 + threadIdx.x;
        const float4* src = (const float4*)svd_up + (size_t)t * 4;
        #pragma unroll
        for (int h = 0; h < 2; ++h) {
            const float4 a = src[h * 2], c = src[h * 2 + 1];
            u16x8 v;
            v[0] = f2bf(a.x); v[1] = f2bf(a.y); v[2] = f2bf(a.z); v[3] = f2bf(a.w);
            v[4] = f2bf(c.x); v[5] = f2bf(c.y); v[6] = f2bf(c.z); v[7] = f2bf(c.w);
            *(u16x8*)(upb + (size_t)t * 16 + h * 8) = v;
        }
    }
}

// ---------------------------------------------------------------------------
// Kernel 2: W dequant via bf16 MFMA correction (unchanged from R3).
// ---------------------------------------------------------------------------
__global__ __launch_bounds__(256) void w_pass1_mfma_kernel(
    const int* __restrict__ Wq, const float* __restrict__ scale,
    const float* __restrict__ zp,
    const unsigned short* __restrict__ upb,
    const unsigned short* __restrict__ dnt,
    float* __restrict__ Wf, float* __restrict__ partial_max)
{
    const int lane = threadIdx.x & 63, wid = threadIdx.x >> 6;
    const int wm = wid >> 1, wn = wid & 1;
    const int l15 = lane & 15, l16 = lane >> 4;
    const int row0 = blockIdx.x * 64 + wm * 32;
    const int col0 = blockIdx.y * 128 + wn * 64;

    short8 af[2][4], bfr[4][4];
    #pragma unroll
    for (int mi = 0; mi < 2; ++mi)
        #pragma unroll
        for (int kk = 0; kk < 4; ++kk)
            af[mi][kk] = *(const short8*)(upb +
                (size_t)(row0 + mi * 16 + l15) * RANK + kk * 32 + l16 * 8);
    #pragma unroll
    for (int ni = 0; ni < 4; ++ni)
        #pragma unroll
        for (int kk = 0; kk < 4; ++kk)
            bfr[ni][kk] = *(const short8*)(dnt +
                (size_t)(col0 + ni * 16 + l15) * RANK + kk * 32 + l16 * 8);

    f32x4 acc[2][4];
    #pragma unroll
    for (int mi = 0; mi < 2; ++mi)
        #pragma unroll
        for (int ni = 0; ni < 4; ++ni) acc[mi][ni] = (f32x4){0.f, 0.f, 0.f, 0.f};

    #pragma unroll
    for (int kk = 0; kk < 4; ++kk)
        #pragma unroll
        for (int mi = 0; mi < 2; ++mi)
            #pragma unroll
            for (int ni = 0; ni < 4; ++ni)
                acc[mi][ni] = __builtin_amdgcn_mfma_f32_16x16x32_bf16(
                    af[mi][kk], bfr[ni][kk], acc[mi][ni], 0, 0, 0);

    float rmax[2][4];
    #pragma unroll
    for (int mi = 0; mi < 2; ++mi)
        #pragma unroll
        for (int j = 0; j < 4; ++j) rmax[mi][j] = 0.f;

    #pragma unroll
    for (int ni = 0; ni < 4; ++ni) {
        const int col = col0 + ni * 16 + l15;
        const int g = col >> 7;
        #pragma unroll
        for (int mi = 0; mi < 2; ++mi) {
            #pragma unroll
            for (int j = 0; j < 4; ++j) {
                const int row = row0 + mi * 16 + l16 * 4 + j;
                const float s = scale[row * NG + g];
                const float z = zp[row * NG + g];
                const float q = (float)Wq[(size_t)row * KDIM + col];
                const float wf = (q - z) * s + acc[mi][ni][j];
                Wf[(size_t)row * KDIM + col] = wf;
                rmax[mi][j] = fmaxf(rmax[mi][j], fabsf(wf));
            }
        }
    }

    #pragma unroll
    for (int mi = 0; mi < 2; ++mi) {
        #pragma unroll
        for (int j = 0; j < 4; ++j) {
            float v = rmax[mi][j];
            v = fmaxf(v, __shfl_xor(v, 1, 64));
            v = fmaxf(v, __shfl_xor(v, 2, 64));
            v = fmaxf(v, __shfl_xor(v, 4, 64));
            v = fmaxf(v, __shfl_xor(v, 8, 64));
            if (l15 == 0) {
                const int row = row0 + mi * 16 + l16 * 4 + j;
                partial_max[(size_t)row * NCHUNK + blockIdx.y * 2 + wn] = v;
            }
        }
    }
}

__global__ __launch_bounds__(256) void finalize_sw_kernel(
    const float* __restrict__ partial_max, float* __restrict__ scale_w)
{
    const int o = blockIdx.x * 256 + threadIdx.x;
    const float4* p = (const float4*)(partial_max + (size_t)o * NCHUNK);
    float m = 0.f;
    #pragma unroll
    for (int i = 0; i < NCHUNK / 4; ++i) {
        const float4 v = p[i];
        m = fmaxf(m, fmaxf(fmaxf(v.x, v.y), fmaxf(v.z, v.w)));
    }
    scale_w[o] = m / 127.0f;
}

__global__ __launch_bounds__(256) void w_quant_kernel(
    const float* __restrict__ Wf, const float* __restrict__ scale_w,
    int8_t* __restrict__ wq)
{
    const size_t idx = ((size_t)blockIdx.x * 256 + threadIdx.x) * 4;
    const int o = (int)(idx >> 12);
    const float sw = scale_w[o];
    const float4 wf = *(const float4*)(Wf + idx);
    char4 q;
    q.x = (char)fminf(fmaxf(rintf(wf.x / sw), -128.f), 127.f);
    q.y = (char)fminf(fmaxf(rintf(wf.y / sw), -128.f), 127.f);
    q.z = (char)fminf(fmaxf(rintf(wf.z / sw), -128.f), 127.f);
    q.w = (char)fminf(fmaxf(rintf(wf.w / sw), -128.f), 127.f);
    *(char4*)(wq + idx) = q;
}

// ---------------------------------------------------------------------------
// Kernel 4: int8 GEMM, 256x256, BK=64, 8 waves — 4-PHASE schedule.
// Changes vs R2/R3 8-phase: (a) 16 MFMA per phase (one A-quadrant x full B;
// Br held in regs across the pair) -> half the barriers; (b) XOR bank-swizzle
// on LDS: read slot = l16 ^ ((l15>>1)&3) (lane-constant: sigma(row)=(row>>1)&3
// is invariant under the +16-row fragment steps), inverse-permuted GLOBAL
// source col on stage (linear LDS dest, per m173/m201 both-sides rule).
//
// Choreography per iter i (tiles 2i in buf0, 2i+1 in buf1), stage kt clamped
// at the tail (dummies keep vmcnt uniform; never read):
//   ph1: rd buf0{A-q0,B}    stage buf1.A<-2i+1         (buf1.A last rd prev ph4)
//   ph2: rd buf0{A-q1}      stage buf0.B<-2i+2 vmcnt(2)(buf0.B last rd ph1)
//   ph3: rd buf1{A-q0,B}    stage buf0.A<-2i+2         (buf0.A last rd ph2)
//   ph4: rd buf1{A-q1}      stage buf1.B<-2i+3 vmcnt(2)(buf1.B last rd ph3)
// vmcnt(2)@ph2: in flight {prevB1x2,A1x2,B0x2} -> drains prevB1+A1 = buf1
//   complete before ph3 reads.  vmcnt(2)@ph4: drains B0+A0 = buf0 complete
//   before next ph1.  Reads of phase p are lgkm-drained before p's MFMA,
//   hence before p's end barrier -> stages in p+1 never overwrite live data.
// ---------------------------------------------------------------------------
__global__ __launch_bounds__(512, 2) void gemm_i8_kernel(
    const int8_t* __restrict__ Aq,   // [T][K]
    const int8_t* __restrict__ Bq,   // [N][K]
    const float* __restrict__ scale_x, const float* __restrict__ scale_w,
    const float* __restrict__ bias, float* __restrict__ out)
{
    __shared__ __align__(16) int8_t lds[65536];
    // A: db*16384 + h*8192 (128 rows x 64B); B: +32768 same.

    const int tid  = threadIdx.x;
    const int lane = tid & 63;
    const int wid  = tid >> 6;
    const int wmp  = wid >> 2;
    const int wnp  = wid & 3;
    const int l15  = lane & 15, l16 = lane >> 4;

    const int swz  = (blockIdx.x & 7) * 32 + (blockIdx.x >> 3);
    const int row0 = (swz >> 4) * 256;
    const int col0 = (swz & 15) * 256;

    // staging: LDS dest linear (base+lane*16); global source col inverse-
    // swizzled: slot ^ sigma(srow), sigma(srow) = (srow>>1)&3 = (lane>>3)&3.
    const int srow = wid * 16 + (lane >> 2);
    const int scol = ((lane & 3) ^ ((lane >> 3) & 3)) * 16;
    const int8_t* const A0 = Aq + (size_t)(row0 + srow) * KDIM + scol;
    const int8_t* const B0 = Bq + (size_t)(col0 + srow) * KDIM + scol;
    int8_t* const ldsw = lds + wid * 1024;

#define STAGE_A(db, h, kt) \
    __builtin_amdgcn_global_load_lds( \
        (const __attribute__((address_space(1))) void*)(A0 + (size_t)(h) * 128 * KDIM + (kt) * 64), \
        (__attribute__((address_space(3))) void*)(ldsw + (db) * 16384 + (h) * 8192), 16, 0, 0)
#define STAGE_B(db, h, kt) \
    __builtin_amdgcn_global_load_lds( \
        (const __attribute__((address_space(1))) void*)(B0 + (size_t)(h) * 128 * KDIM + (kt) * 64), \
        (__attribute__((address_space(3))) void*)(ldsw + 32768 + (db) * 16384 + (h) * 8192), 16, 0, 0)

    // swizzled read slot (lane-constant)
    const int rslot = ((l16 ^ ((lane >> 1) & 3))) * 16;
    const int aoff = wmp * 8192 + l15 * 64 + rslot;
    const int boff = 32768 + (wnp >> 1) * 8192 + (wnp & 1) * 4096 + l15 * 64 + rslot;

    i32x4 Ar[4], Br[2][2];
    i32x4 acc[8][4];
    #pragma unroll
    for (int m = 0; m < 8; ++m)
        #pragma unroll
        for (int n = 0; n < 4; ++n) acc[m][n] = (i32x4){0, 0, 0, 0};

#define LDA(db, qm) { const int8_t* p = lds + (db) * 16384 + aoff + (qm) * 4096; \
    Ar[0] = *(const i32x4*)(p);        Ar[1] = *(const i32x4*)(p + 1024); \
    Ar[2] = *(const i32x4*)(p + 2048); Ar[3] = *(const i32x4*)(p + 3072); }
#define LDB(db, qn) { const int8_t* p = lds + (db) * 16384 + boff + (qn) * 2048; \
    Br[qn][0] = *(const i32x4*)(p);    Br[qn][1] = *(const i32x4*)(p + 1024); }
#define MMA(qm, qn) { \
    _Pragma("unroll") for (int fm = 0; fm < 4; ++fm) \
    _Pragma("unroll") for (int fn = 0; fn < 2; ++fn) \
        acc[(qm) * 4 + fm][(qn) * 2 + fn] = __builtin_amdgcn_mfma_i32_16x16x64_i8( \
            Ar[fm], Br[qn][fn], acc[(qm) * 4 + fm][(qn) * 2 + fn], 0, 0, 0); }

#define FENCE asm volatile("" ::: "memory")
#define BAR   __builtin_amdgcn_s_barrier()
#define VMCNT2 asm volatile("s_waitcnt vmcnt(2)" ::: "memory")
#define PRIO1 __builtin_amdgcn_s_setprio(1)
#define PRIO0 __builtin_amdgcn_s_setprio(0)

    // prologue: tile0 -> buf0 (4 loads); tile1.B -> buf1 (2 loads)
    STAGE_A(0, 0, 0); STAGE_A(0, 1, 0); STAGE_B(0, 0, 0); STAGE_B(0, 1, 0);
    STAGE_B(1, 0, 1); STAGE_B(1, 1, 1);
    VMCNT2;            // buf0 complete; B1x2 in flight
    BAR;

    for (int i = 0; i < 32; ++i) {
        const int kt1 = 2 * i + 1;
        const int kt2 = (2 * i + 2 > 63) ? 63 : 2 * i + 2;
        const int kt3 = (2 * i + 3 > 63) ? 63 : 2 * i + 3;

        // ph1: tile 2i, A-quadrant 0, full B
        LDA(0, 0); LDB(0, 0); LDB(0, 1);
        FENCE; STAGE_A(1, 0, kt1); STAGE_A(1, 1, kt1);
        BAR; PRIO1; MMA(0, 0); MMA(0, 1); PRIO0; BAR;

        // ph2: tile 2i, A-quadrant 1 (Br reused)
        LDA(0, 1);
        FENCE; STAGE_B(0, 0, kt2); STAGE_B(0, 1, kt2); VMCNT2;
        BAR; PRIO1; MMA(1, 0); MMA(1, 1); PRIO0; BAR;

        // ph3: tile 2i+1, A-quadrant 0, full B
        LDA(1, 0); LDB(1, 0); LDB(1, 1);
        FENCE; STAGE_A(0, 0, kt2); STAGE_A(0, 1, kt2);
        BAR; PRIO1; MMA(0, 0); MMA(0, 1); PRIO0; BAR;

        // ph4: tile 2i+1, A-quadrant 1
        LDA(1, 1);
        FENCE; STAGE_B(1, 0, kt3); STAGE_B(1, 1, kt3); VMCNT2;
        BAR; PRIO1; MMA(1, 0); MMA(1, 1); PRIO0; BAR;
    }

    // epilogue: C/D layout col = lane&15, row = (lane>>4)*4 + reg
    const int orow0 = row0 + wmp * 128;
    const int ocol0 = col0 + wnp * 64;
    #pragma unroll
    for (int fn = 0; fn < 4; ++fn) {
        const int col = ocol0 + fn * 16 + l15;
        const float sw = scale_w[col];
        const float bv = bias[col];
        #pragma unroll
        for (int fm = 0; fm < 8; ++fm) {
            #pragma unroll
            for (int j = 0; j < 4; ++j) {
                const int row = orow0 + fm * 16 + l16 * 4 + j;
                out[(size_t)row * NDIM + col] =
                    (float)acc[fm][fn][j] * scale_x[row] * sw + bv;
            }
        }
    }
#undef STAGE_A
#undef STAGE_B
#undef LDA
#undef LDB
#undef MMA
#undef FENCE
#undef BAR
#undef VMCNT2
#undef PRIO1
#undef PRIO0
}

// ---------------------------------------------------------------------------
extern "C" void kernel_launch(void* const* d_in, const int* in_sizes, int n_in,
                              void* d_out, int out_size, void* d_ws, size_t ws_size,
                              hipStream_t stream)
{
    const float* x        = (const float*)d_in[0];
    const int*   Wq       = (const int*)d_in[1];
    const float* scale    = (const float*)d_in[2];
    const float* zp       = (const float*)d_in[3];
    const float* svd_up   = (const float*)d_in[4];
    const float* svd_down = (const float*)d_in[5];
    const float* bias     = (const float*)d_in[6];
    float* out = (float*)d_out;

    // ws: xq 16MB | wq 16MB | scale_x 16KB | scale_w 16KB | partial 1MB |
    //     upb 1MB | dnt 1MB
    int8_t* xq = (int8_t*)d_ws;
    int8_t* wq = (int8_t*)d_ws + ((size_t)16 << 20);
    float* scale_x = (float*)((char*)d_ws + ((size_t)32 << 20));
    float* scale_w = scale_x + TDIM;
    float* partial_max = scale_w + NDIM;
    unsigned short* upb = (unsigned short*)(partial_max + (size_t)NDIM * NCHUNK);
    unsigned short* dnt = upb + (size_t)NDIM * RANK;

    // d_out doubles as fp32 Wf scratch (64MB) — fully overwritten by the GEMM.
    float* Wf = out;

    quant_x_kernel<<<TDIM, 256, 0, stream>>>(x, xq, scale_x);
    conv_svd_kernel<<<384, 256, 0, stream>>>(svd_up, svd_down, upb, dnt);
    w_pass1_mfma_kernel<<<dim3(NDIM / 64, KDIM / 128), 256, 0, stream>>>(
        Wq, scale, zp, upb, dnt, Wf, partial_max);
    finalize_sw_kernel<<<NDIM / 256, 256, 0, stream>>>(partial_max, scale_w);
    w_quant_kernel<<<(size_t)NDIM * KDIM / (256 * 4), 256, 0, stream>>>(Wf, scale_w, wq);
    gemm_i8_kernel<<<(TDIM / 256) * (NDIM / 256), 512, 0, stream>>>(
        xq, wq, scale_x, scale_w, bias, out);
}